// Round 3
// baseline (264.674 us; speedup 1.0000x reference)
//
#include <hip/hip_runtime.h>

typedef __bf16 bf16x8 __attribute__((ext_vector_type(8)));
typedef float  f32x4  __attribute__((ext_vector_type(4)));

union U8 { uint4 v; unsigned short u[8]; };

static __device__ __forceinline__ float bf2f(unsigned short u) {
    union { unsigned int i; float f; } c; c.i = ((unsigned int)u) << 16; return c.f;
}
static __device__ __forceinline__ unsigned short f2bf(float f) {
    union { float f; unsigned int i; } c; c.f = f;
    unsigned int x = c.i;
    unsigned int r = (x + 0x7FFFu + ((x >> 16) & 1u)) >> 16;  // RNE
    return (unsigned short)r;
}

static __device__ __forceinline__ U8 load8(const float* p) {
    U8 r;
    const float4 a = *(const float4*)p;
    const float4 b = *(const float4*)(p + 4);
    r.u[0] = f2bf(a.x); r.u[1] = f2bf(a.y); r.u[2] = f2bf(a.z); r.u[3] = f2bf(a.w);
    r.u[4] = f2bf(b.x); r.u[5] = f2bf(b.y); r.u[6] = f2bf(b.z); r.u[7] = f2bf(b.w);
    return r;
}

// async global->LDS, 16B per lane. LDS dest must be wave-uniform base (+lane*16 by HW).
static __device__ __forceinline__ void gld_lds16(const void* g, void* l) {
    __builtin_amdgcn_global_load_lds(
        (const __attribute__((address_space(1))) unsigned int*)g,
        (__attribute__((address_space(3))) unsigned int*)l, 16, 0, 0);
}

// ---- merged pack pass: bid<2048: x f32->bf16 + bias concat; else weight transpose ----
// wAllT[640][512] = [wq^T | wk^T | wv^T], woT[512][512], ball[640] = [bq|bk|bv]
__global__ __launch_bounds__(256)
void pack(const float* __restrict__ x, unsigned short* __restrict__ xb,
          const float* __restrict__ bq, const float* __restrict__ bk,
          const float* __restrict__ bv, float* __restrict__ ball,
          const float* __restrict__ wv, const float* __restrict__ wo,
          const float* __restrict__ wq, const float* __restrict__ wk,
          unsigned short* __restrict__ wAllT, unsigned short* __restrict__ woT)
{
    const int bid = blockIdx.x, t = threadIdx.x;
    if (bid < 2048) {
        const long i = ((long)bid * 256 + t) * 16;
        U8 a = load8(x + i);
        U8 b = load8(x + i + 8);
        *(uint4*)(xb + i) = a.v;
        *(uint4*)(xb + i + 8) = b.v;
        if (bid == 0) {
            ball[t]       = t < 64 ? bq[t] : (t < 128 ? bk[t - 64] : bv[t - 128]);
            ball[t + 256] = bv[t + 128];
            if (t < 128) ball[t + 512] = bv[t + 384];
        }
        return;
    }
    // transpose+convert: dst[C][R] = src[R][C]^T, 64x64 tiles
    __shared__ float sT[64][65];
    const int b2 = bid - 2048;
    const int zz = b2 >> 6, rem = b2 & 63;
    const int cx = rem & 7, ry = rem >> 3;
    const float* src; unsigned short* dst; int C;
    if      (zz == 0) { src = wv; dst = wAllT + 128 * 512; C = 512; }
    else if (zz == 1) { src = wo; dst = woT;               C = 512; }
    else if (zz == 2) { src = wq; dst = wAllT;             C = 64;  }
    else              { src = wk; dst = wAllT + 64 * 512;  C = 64;  }
    const int R = 512;
    const int c0 = cx * 64, r0 = ry * 64;
    if (c0 >= C) return;
    #pragma unroll
    for (int k = 0; k < 16; ++k) {
        const int lin = k * 256 + t;
        const int i = lin >> 6, j = lin & 63;
        sT[i][j] = src[(long)(r0 + i) * C + c0 + j];
    }
    __syncthreads();
    #pragma unroll
    for (int k = 0; k < 16; ++k) {
        const int lin = k * 256 + t;
        const int o = lin >> 6, i2 = lin & 63;
        dst[(long)(c0 + o) * R + r0 + i2] = f2bf(sT[i2][o]);
    }
}

// ---- m97-structure GEMM: C[M][N] = A[M][K]bf16 @ B^T[N][K]bf16 ----
// 128x128 tile, BK=64, 4 waves, global_load_lds + XOR-swizzle (rule 21 involution).
// MIXED (fused QKV): colBase<128 -> QK interleaved bf16 (ldc=128); else transposed
// store into VT[bat][col-128][key]. TRANSC kept for standalone use (unused now).
template<bool BIAS, bool RES, bool OUT_F32, bool TRANSC, bool MIXED>
__global__ __launch_bounds__(256, 4)
void gemm128(const unsigned short* __restrict__ A, int lda,
             const unsigned short* __restrict__ B, int ldb,
             void* __restrict__ Cp, int ldc,
             void* __restrict__ Cp2,
             const float* __restrict__ bias,
             const float* __restrict__ resid,
             int K)
{
    __shared__ __align__(16) unsigned short sA[128 * 64];  // 16 KB
    __shared__ __align__(16) unsigned short sB[128 * 64];  // 16 KB

    const int t = threadIdx.x, wave = t >> 6, lane = t & 63;
    const int lr = lane & 15, quad = lane >> 4;
    const int rowBase = blockIdx.y * 128, colBase = blockIdx.x * 128;
    const int wm = (wave >> 1) * 64, wn = (wave & 1) * 64;

    const int srow  = lane >> 3;
    const int sslot = lane & 7;

    f32x4 acc[4][4];
    #pragma unroll
    for (int mt = 0; mt < 4; ++mt)
        #pragma unroll
        for (int nt = 0; nt < 4; ++nt) acc[mt][nt] = (f32x4){0.f, 0.f, 0.f, 0.f};

    for (int kt = 0; kt < K; kt += 64) {
        #pragma unroll
        for (int is = 0; is < 4; ++is) {
            const int r0  = wave * 32 + is * 8;
            const int row = r0 + srow;
            const int swz = (sslot ^ (row & 7)) << 4;
            gld_lds16((const char*)A + ((long)(rowBase + row) * lda + kt) * 2 + swz,
                      (char*)sA + r0 * 128);
            gld_lds16((const char*)B + ((long)(colBase + row) * ldb + kt) * 2 + swz,
                      (char*)sB + r0 * 128);
        }
        __syncthreads();

        #pragma unroll
        for (int ks = 0; ks < 2; ++ks) {
            const int kb = ks * 64 + quad * 16;
            bf16x8 bfr[4];
            #pragma unroll
            for (int nt = 0; nt < 4; ++nt) {
                const int row = wn + nt * 16 + lr;
                bfr[nt] = *(const bf16x8*)((const char*)sB + row * 128 + (kb ^ ((row & 7) << 4)));
            }
            #pragma unroll
            for (int mt = 0; mt < 4; ++mt) {
                const int row = wm + mt * 16 + lr;
                bf16x8 af = *(const bf16x8*)((const char*)sA + row * 128 + (kb ^ ((row & 7) << 4)));
                #pragma unroll
                for (int nt = 0; nt < 4; ++nt)
                    acc[mt][nt] = __builtin_amdgcn_mfma_f32_16x16x32_bf16(af, bfr[nt], acc[mt][nt], 0, 0, 0);
            }
        }
        __syncthreads();
    }

    float* Cf = (float*)Cp;
    unsigned short* Cb = (unsigned short*)Cp;
    unsigned short* C2 = (unsigned short*)Cp2;
    #pragma unroll
    for (int mt = 0; mt < 4; ++mt)
        #pragma unroll
        for (int nt = 0; nt < 4; ++nt) {
            const int row0 = rowBase + wm + mt * 16 + quad * 4;
            const int col  = colBase + wn + nt * 16 + lr;
            const float b = BIAS ? bias[col] : 0.f;
            if (MIXED && colBase >= 128) {
                // transposed store into VT[bat][col-128][key]
                const int bat = row0 >> 11, key = row0 & 2047;
                ushort4 v4;
                v4.x = f2bf(acc[mt][nt][0] + b);
                v4.y = f2bf(acc[mt][nt][1] + b);
                v4.z = f2bf(acc[mt][nt][2] + b);
                v4.w = f2bf(acc[mt][nt][3] + b);
                *(ushort4*)&C2[((long)bat * 512 + (col - 128)) * 2048 + key] = v4;
            } else if (TRANSC) {
                const int bat = row0 >> 11, key = row0 & 2047;
                ushort4 v4;
                v4.x = f2bf(acc[mt][nt][0] + b);
                v4.y = f2bf(acc[mt][nt][1] + b);
                v4.z = f2bf(acc[mt][nt][2] + b);
                v4.w = f2bf(acc[mt][nt][3] + b);
                *(ushort4*)&C2[((long)bat * 512 + col) * 2048 + key] = v4;
            } else {
                #pragma unroll
                for (int r = 0; r < 4; ++r) {
                    const int row = row0 + r;
                    float v = acc[mt][nt][r] + b;
                    if (RES)     v += resid[(long)row * ldc + col];
                    if (OUT_F32) Cf[(long)row * ldc + col] = v;
                    else         Cb[(long)row * ldc + col] = f2bf(v);
                }
            }
        }
}

// Fused attention. Re-tiled: block = 32 Q-rows x 256 V-cols (1024 blocks, 4/CU).
// The 4 waves PARTITION the S/exp work (wave = row-group x key-half) instead of
// duplicating it: per-thread exp/cvt/ds_write per tile halves (16 -> 8).
// Each wave owns O[32 rows][64 cols]. Native (__bf16) cast = v_cvt_pk RNE.
__global__ __launch_bounds__(256, 4)
void flash_attn(const unsigned short* __restrict__ QK,  // [8*2048][128] (Q|K)
                const unsigned short* __restrict__ VT,  // [8][512][2048]
                unsigned short* __restrict__ O)         // [8*2048][512]
{
    __shared__ __align__(16) unsigned short sK[2][64 * 64];   // 2 x 8 KB
    __shared__ __align__(16) unsigned short sP[2][32 * 72];   // 2 x 4.5 KB
    __shared__ float sL[2][32];

    const int bid = blockIdx.x;
    const int z  = bid & 7;          // batch -> XCD (round-robin dispatch)
    const int rr = bid >> 3;
    const int cs = rr & 1;           // 256-col split
    const int qt = rr >> 1;          // 64 Q-tiles of 32 rows

    const int t = threadIdx.x, wave = t >> 6, lane = t & 63;
    const int lr = lane & 15, quad = lane >> 4;
    const int srg = wave & 1;        // S row-group this wave computes
    const int skg = wave >> 1;       // S key-half (32 of 64 keys)

    const long qrow0 = (long)z * 2048 + qt * 32;
    // Q A-frags for S rows srg*16+lr
    const unsigned short* qp = QK + (qrow0 + srg * 16 + lr) * 128 + quad * 8;
    const bf16x8 qa0 = *(const bf16x8*)(qp);
    const bf16x8 qa1 = *(const bf16x8*)(qp + 32);

    // K rows at QK[z*2048+key][64..127]: 256 B row stride
    const char* Kb = (const char*)(QK + (long)z * 2048 * 128 + 64);
    const unsigned short* Vb = VT + (long)z * 512 * 2048
                                  + ((long)cs * 256 + wave * 64) * 2048;

    // staging: wave stages keys wave*16..+15; PRE-SWIZZLED source, linear LDS
    const long stg_go = (long)(wave * 16 + (lane >> 3)) * 256
                      + (((lane & 7) ^ (lane >> 3)) << 4);
    const int swq = (lr & 7) << 4;   // read-side XOR, (key&7)==(lr&7)

    f32x4 acc[2][4];   // [mt][nt]: rows mt*16+quad*4+r, cols wave*64+nt*16+lr
    #pragma unroll
    for (int mt = 0; mt < 2; ++mt)
        #pragma unroll
        for (int nt = 0; nt < 4; ++nt) acc[mt][nt] = (f32x4){0.f, 0.f, 0.f, 0.f};
    float lsum[4] = {0.f, 0.f, 0.f, 0.f};

    {   // prologue: stage K tile 0 into sK[0]
        const char* gk = Kb + stg_go;
        char* lk = (char*)sK[0] + wave * 2048;
        gld_lds16(gk, lk);
        gld_lds16(gk + 2048, lk + 1024);
    }
    __syncthreads();

    int cur = 0;
    for (int kt = 0; kt < 32; ++kt) {
        const int key0 = kt * 64;

        // prefetch V frags for THIS tile (hide L2 latency under S-phase)
        bf16x8 vv[4][2];
        #pragma unroll
        for (int nt = 0; nt < 4; ++nt) {
            const unsigned short* vp = Vb + (long)(nt * 16 + lr) * 2048 + key0 + quad * 8;
            vv[nt][0] = *(const bf16x8*)(vp);
            vv[nt][1] = *(const bf16x8*)(vp + 32);
        }

        // async-stage NEXT K tile
        if (kt < 31) {
            const char* gk = Kb + (long)(kt + 1) * 16384 + stg_go;
            char* lk = (char*)sK[cur ^ 1] + wave * 2048;
            gld_lds16(gk, lk);
            gld_lds16(gk + 2048, lk + 1024);
        }

        // S: this wave's 16 rows x its 32-key half (partitioned, no duplication)
        const char* sKc = (const char*)sK[cur];
        __bf16* sPb = (__bf16*)sP[cur];
        #pragma unroll
        for (int g = 0; g < 2; ++g) {
            const int key = skg * 32 + g * 16 + lr;
            const int kb = key * 128;
            bf16x8 k0 = *(const bf16x8*)(sKc + kb + ((quad * 16) ^ swq));
            bf16x8 k1 = *(const bf16x8*)(sKc + kb + ((quad * 16 + 64) ^ swq));
            f32x4 sv = (f32x4){0.f, 0.f, 0.f, 0.f};
            sv = __builtin_amdgcn_mfma_f32_16x16x32_bf16(qa0, k0, sv, 0, 0, 0);
            sv = __builtin_amdgcn_mfma_f32_16x16x32_bf16(qa1, k1, sv, 0, 0, 0);
            #pragma unroll
            for (int r = 0; r < 4; ++r) {
                const float e = __expf(sv[r]);
                const __bf16 pb = (__bf16)e;       // v_cvt RNE (== manual f2bf)
                lsum[r] += (float)pb;
                sPb[(srg * 16 + quad * 4 + r) * 72 + skg * 32 + g * 16 + lr] = pb;
            }
        }

        __syncthreads();   // publishes sP[cur], drains async sK[cur^1]

        // O += P V
        const char* sPc = (const char*)sP[cur];
        bf16x8 p[2][2];
        #pragma unroll
        for (int mt = 0; mt < 2; ++mt) {
            const char* pp = sPc + (mt * 16 + lr) * 144 + quad * 16;
            p[mt][0] = *(const bf16x8*)(pp);
            p[mt][1] = *(const bf16x8*)(pp + 64);
        }
        __builtin_amdgcn_s_setprio(1);
        #pragma unroll
        for (int mt = 0; mt < 2; ++mt)
            #pragma unroll
            for (int nt = 0; nt < 4; ++nt) {
                acc[mt][nt] = __builtin_amdgcn_mfma_f32_16x16x32_bf16(p[mt][0], vv[nt][0], acc[mt][nt], 0, 0, 0);
                acc[mt][nt] = __builtin_amdgcn_mfma_f32_16x16x32_bf16(p[mt][1], vv[nt][1], acc[mt][nt], 0, 0, 0);
            }
        __builtin_amdgcn_s_setprio(0);
        cur ^= 1;
    }

    // row sums: reduce over 16 lr lanes, combine the two key-half waves via LDS
    #pragma unroll
    for (int r = 0; r < 4; ++r) {
        float v = lsum[r];
        v += __shfl_xor(v, 1); v += __shfl_xor(v, 2);
        v += __shfl_xor(v, 4); v += __shfl_xor(v, 8);
        lsum[r] = v;
    }
    if (lr == 0) {
        #pragma unroll
        for (int r = 0; r < 4; ++r) sL[skg][srg * 16 + quad * 4 + r] = lsum[r];
    }
    __syncthreads();

    #pragma unroll
    for (int mt = 0; mt < 2; ++mt) {
        float inv[4];
        #pragma unroll
        for (int r = 0; r < 4; ++r) {
            const int rl = mt * 16 + quad * 4 + r;
            inv[r] = 1.0f / (sL[0][rl] + sL[1][rl]);
        }
        #pragma unroll
        for (int nt = 0; nt < 4; ++nt) {
            const int col = cs * 256 + wave * 64 + nt * 16 + lr;
            #pragma unroll
            for (int r = 0; r < 4; ++r) {
                const long row = qrow0 + mt * 16 + quad * 4 + r;
                O[row * 512 + col] = f2bf(acc[mt][nt][r] * inv[r]);
            }
        }
    }
}

extern "C" void kernel_launch(void* const* d_in, const int* in_sizes, int n_in,
                              void* d_out, int out_size, void* d_ws, size_t ws_size,
                              hipStream_t stream)
{
    const float* x  = (const float*)d_in[0];
    const float* wq = (const float*)d_in[1];
    const float* bq = (const float*)d_in[2];
    const float* wk = (const float*)d_in[3];
    const float* bk = (const float*)d_in[4];
    const float* wv = (const float*)d_in[5];
    const float* bv = (const float*)d_in[6];
    const float* wo = (const float*)d_in[7];
    const float* bo = (const float*)d_in[8];

    const int W = 512;
    float* out = (float*)d_out;
    dim3 blk(256);
    char* ws = (char*)d_ws;

    const size_t NEED = 56ull << 20;
    if (ws_size < NEED) return;  // zero-output signature

    unsigned short* QK    = (unsigned short*)(ws);                  //  4 MB [16384 x 128] (Q|K)
    unsigned short* VT    = (unsigned short*)(ws + ( 4ull << 20));  // 16 MB [8][512][2048]
    unsigned short* O     = (unsigned short*)(ws + (20ull << 20));  // 16 MB [16384 x 512]
    unsigned short* xb    = (unsigned short*)(ws + (36ull << 20));  // 16 MB [16384 x 512]
    unsigned short* wAllT = (unsigned short*)(ws + (52ull << 20));  // 640 KB [640][512]
    unsigned short* woT   = (unsigned short*)(ws + (53ull << 20));  // 512 KB [512][512]
    float*          ball  = (float*)         (ws + (53ull << 20) + (512ull << 10)); // 2.5 KB

    // pack: x->bf16, bias concat, weights -> bf16 B^T layouts (merged launch)
    pack<<<dim3(2048 + 256), blk, 0, stream>>>(x, xb, bq, bk, bv, ball,
                                               wv, wo, wq, wk, wAllT, woT);

    // Fused QKV projection: [QK | V] = xb @ [wq|wk|wv] + [bq|bk|bv]
    // cols 0-127 -> QK interleaved, cols 128-639 -> VT transposed store
    gemm128<true, false, false, false, true><<<dim3(5, 128), blk, 0, stream>>>(
        xb, W, wAllT, W, QK, 128, VT, ball, nullptr, W);

    // Fused attention (no S): O = softmax(Q K^T) V
    flash_attn<<<dim3(1024), blk, 0, stream>>>(QK, VT, O);

    // out = O @ wo + bo + x  (fp32)
    gemm128<true, true, true, false, false><<<dim3(4, 128), blk, 0, stream>>>(
        O, W, woT, W, out, W, nullptr, bo, x, W);
}

// Round 4
// 219.305 us; speedup vs baseline: 1.2069x; 1.2069x over previous
//
#include <hip/hip_runtime.h>

typedef __bf16 bf16x8 __attribute__((ext_vector_type(8)));
typedef float  f32x4  __attribute__((ext_vector_type(4)));

union U8 { uint4 v; unsigned short u[8]; };

static __device__ __forceinline__ float bf2f(unsigned short u) {
    union { unsigned int i; float f; } c; c.i = ((unsigned int)u) << 16; return c.f;
}
static __device__ __forceinline__ unsigned short f2bf(float f) {
    union { float f; unsigned int i; } c; c.f = f;
    unsigned int x = c.i;
    unsigned int r = (x + 0x7FFFu + ((x >> 16) & 1u)) >> 16;  // RNE
    return (unsigned short)r;
}

static __device__ __forceinline__ U8 load8(const float* p) {
    U8 r;
    const float4 a = *(const float4*)p;
    const float4 b = *(const float4*)(p + 4);
    r.u[0] = f2bf(a.x); r.u[1] = f2bf(a.y); r.u[2] = f2bf(a.z); r.u[3] = f2bf(a.w);
    r.u[4] = f2bf(b.x); r.u[5] = f2bf(b.y); r.u[6] = f2bf(b.z); r.u[7] = f2bf(b.w);
    return r;
}

// async global->LDS, 16B per lane. LDS dest must be wave-uniform base (+lane*16 by HW).
static __device__ __forceinline__ void gld_lds16(const void* g, void* l) {
    __builtin_amdgcn_global_load_lds(
        (const __attribute__((address_space(1))) unsigned int*)g,
        (__attribute__((address_space(3))) unsigned int*)l, 16, 0, 0);
}

// ---- merged pack pass: bid<2048: x f32->bf16 + bias concat; else weight transpose ----
// wAllT[640][512] = [wq^T | wk^T | wv^T], woT[512][512], ball[640] = [bq|bk|bv]
__global__ __launch_bounds__(256)
void pack(const float* __restrict__ x, unsigned short* __restrict__ xb,
          const float* __restrict__ bq, const float* __restrict__ bk,
          const float* __restrict__ bv, float* __restrict__ ball,
          const float* __restrict__ wv, const float* __restrict__ wo,
          const float* __restrict__ wq, const float* __restrict__ wk,
          unsigned short* __restrict__ wAllT, unsigned short* __restrict__ woT)
{
    const int bid = blockIdx.x, t = threadIdx.x;
    if (bid < 2048) {
        const long i = ((long)bid * 256 + t) * 16;
        U8 a = load8(x + i);
        U8 b = load8(x + i + 8);
        *(uint4*)(xb + i) = a.v;
        *(uint4*)(xb + i + 8) = b.v;
        if (bid == 0) {
            ball[t]       = t < 64 ? bq[t] : (t < 128 ? bk[t - 64] : bv[t - 128]);
            ball[t + 256] = bv[t + 128];
            if (t < 128) ball[t + 512] = bv[t + 384];
        }
        return;
    }
    // transpose+convert: dst[C][R] = src[R][C]^T, 64x64 tiles
    __shared__ float sT[64][65];
    const int b2 = bid - 2048;
    const int zz = b2 >> 6, rem = b2 & 63;
    const int cx = rem & 7, ry = rem >> 3;
    const float* src; unsigned short* dst; int C;
    if      (zz == 0) { src = wv; dst = wAllT + 128 * 512; C = 512; }
    else if (zz == 1) { src = wo; dst = woT;               C = 512; }
    else if (zz == 2) { src = wq; dst = wAllT;             C = 64;  }
    else              { src = wk; dst = wAllT + 64 * 512;  C = 64;  }
    const int R = 512;
    const int c0 = cx * 64, r0 = ry * 64;
    if (c0 >= C) return;
    #pragma unroll
    for (int k = 0; k < 16; ++k) {
        const int lin = k * 256 + t;
        const int i = lin >> 6, j = lin & 63;
        sT[i][j] = src[(long)(r0 + i) * C + c0 + j];
    }
    __syncthreads();
    #pragma unroll
    for (int k = 0; k < 16; ++k) {
        const int lin = k * 256 + t;
        const int o = lin >> 6, i2 = lin & 63;
        dst[(long)(c0 + o) * R + r0 + i2] = f2bf(sT[i2][o]);
    }
}

// ---- m97-structure GEMM: C[M][N] = A[M][K]bf16 @ B^T[N][K]bf16 ----
// 128x128 tile, BK=64, 4 waves, global_load_lds + XOR-swizzle (rule 21 involution).
// MIXED (fused QKV): colBase<128 -> QK interleaved bf16 (ldc=128); else transposed
// store into VT[bat][col-128][key].
template<bool BIAS, bool RES, bool OUT_F32, bool TRANSC, bool MIXED>
__global__ __launch_bounds__(256, 4)
void gemm128(const unsigned short* __restrict__ A, int lda,
             const unsigned short* __restrict__ B, int ldb,
             void* __restrict__ Cp, int ldc,
             void* __restrict__ Cp2,
             const float* __restrict__ bias,
             const float* __restrict__ resid,
             int K)
{
    __shared__ __align__(16) unsigned short sA[128 * 64];  // 16 KB
    __shared__ __align__(16) unsigned short sB[128 * 64];  // 16 KB

    const int t = threadIdx.x, wave = t >> 6, lane = t & 63;
    const int lr = lane & 15, quad = lane >> 4;
    const int rowBase = blockIdx.y * 128, colBase = blockIdx.x * 128;
    const int wm = (wave >> 1) * 64, wn = (wave & 1) * 64;

    const int srow  = lane >> 3;
    const int sslot = lane & 7;

    f32x4 acc[4][4];
    #pragma unroll
    for (int mt = 0; mt < 4; ++mt)
        #pragma unroll
        for (int nt = 0; nt < 4; ++nt) acc[mt][nt] = (f32x4){0.f, 0.f, 0.f, 0.f};

    for (int kt = 0; kt < K; kt += 64) {
        #pragma unroll
        for (int is = 0; is < 4; ++is) {
            const int r0  = wave * 32 + is * 8;
            const int row = r0 + srow;
            const int swz = (sslot ^ (row & 7)) << 4;
            gld_lds16((const char*)A + ((long)(rowBase + row) * lda + kt) * 2 + swz,
                      (char*)sA + r0 * 128);
            gld_lds16((const char*)B + ((long)(colBase + row) * ldb + kt) * 2 + swz,
                      (char*)sB + r0 * 128);
        }
        __syncthreads();

        #pragma unroll
        for (int ks = 0; ks < 2; ++ks) {
            const int kb = ks * 64 + quad * 16;
            bf16x8 bfr[4];
            #pragma unroll
            for (int nt = 0; nt < 4; ++nt) {
                const int row = wn + nt * 16 + lr;
                bfr[nt] = *(const bf16x8*)((const char*)sB + row * 128 + (kb ^ ((row & 7) << 4)));
            }
            #pragma unroll
            for (int mt = 0; mt < 4; ++mt) {
                const int row = wm + mt * 16 + lr;
                bf16x8 af = *(const bf16x8*)((const char*)sA + row * 128 + (kb ^ ((row & 7) << 4)));
                #pragma unroll
                for (int nt = 0; nt < 4; ++nt)
                    acc[mt][nt] = __builtin_amdgcn_mfma_f32_16x16x32_bf16(af, bfr[nt], acc[mt][nt], 0, 0, 0);
            }
        }
        __syncthreads();
    }

    float* Cf = (float*)Cp;
    unsigned short* Cb = (unsigned short*)Cp;
    unsigned short* C2 = (unsigned short*)Cp2;
    #pragma unroll
    for (int mt = 0; mt < 4; ++mt)
        #pragma unroll
        for (int nt = 0; nt < 4; ++nt) {
            const int row0 = rowBase + wm + mt * 16 + quad * 4;
            const int col  = colBase + wn + nt * 16 + lr;
            const float b = BIAS ? bias[col] : 0.f;
            if (MIXED && colBase >= 128) {
                const int bat = row0 >> 11, key = row0 & 2047;
                ushort4 v4;
                v4.x = f2bf(acc[mt][nt][0] + b);
                v4.y = f2bf(acc[mt][nt][1] + b);
                v4.z = f2bf(acc[mt][nt][2] + b);
                v4.w = f2bf(acc[mt][nt][3] + b);
                *(ushort4*)&C2[((long)bat * 512 + (col - 128)) * 2048 + key] = v4;
            } else if (TRANSC) {
                const int bat = row0 >> 11, key = row0 & 2047;
                ushort4 v4;
                v4.x = f2bf(acc[mt][nt][0] + b);
                v4.y = f2bf(acc[mt][nt][1] + b);
                v4.z = f2bf(acc[mt][nt][2] + b);
                v4.w = f2bf(acc[mt][nt][3] + b);
                *(ushort4*)&C2[((long)bat * 512 + col) * 2048 + key] = v4;
            } else {
                #pragma unroll
                for (int r = 0; r < 4; ++r) {
                    const int row = row0 + r;
                    float v = acc[mt][nt][r] + b;
                    if (RES)     v += resid[(long)row * ldc + col];
                    if (OUT_F32) Cf[(long)row * ldc + col] = v;
                    else         Cb[(long)row * ldc + col] = f2bf(v);
                }
            }
        }
}

// Fused attention — REVERTED to the proven r2 structure (64 Q-rows x 128 V-cols,
// 1024 blocks, 4/CU; each wave computes its own 16 S-rows x 64 keys so the
// S+exp phase covers V/K memory latency — r3's partitioned S starved the
// pipeline and regressed 93->140 us). Grafted micro-opts proven safe in r3:
// native (__bf16) cvt (RNE, == manual f2bf) and s_setprio around PV MFMA (T5).
__global__ __launch_bounds__(256, 4)
void flash_attn(const unsigned short* __restrict__ QK,  // [8*2048][128] (Q|K)
                const unsigned short* __restrict__ VT,  // [8][512][2048]
                unsigned short* __restrict__ O)         // [8*2048][512]
{
    __shared__ __align__(16) unsigned short sK[2][64 * 64];   // 2 x 8 KB
    __shared__ __align__(16) unsigned short sP[2][64 * 72];   // 2 x 9 KB (144B rows, 16B-aligned)
    __shared__ float sL[64];

    const int bid = blockIdx.x;
    const int z  = bid & 7;          // batch -> XCD (round-robin dispatch)
    const int rr = bid >> 3;
    const int cs = rr & 3;           // 128-col split
    const int qt = rr >> 2;          // Q tile (64 rows)

    const int t = threadIdx.x, wave = t >> 6, lane = t & 63;
    const int lr = lane & 15, quad = lane >> 4;

    const long qrow0 = (long)z * 2048 + qt * 64;
    const unsigned short* qp = QK + (qrow0 + wave * 16 + lr) * 128 + quad * 8;
    const bf16x8 qa0 = *(const bf16x8*)(qp);
    const bf16x8 qa1 = *(const bf16x8*)(qp + 32);

    // K rows at QK[z*2048+key][64..127]: 256 B row stride
    const char* Kb = (const char*)(QK + (long)z * 2048 * 128 + 64);
    const unsigned short* Vb = VT + (long)z * 512 * 2048
                                  + ((long)cs * 128 + wave * 32) * 2048;

    // staging: wave stages keys wave*16..+15; PRE-SWIZZLED source, linear LDS
    const long stg_go = (long)(wave * 16 + (lane >> 3)) * 256
                      + (((lane & 7) ^ (lane >> 3)) << 4);
    const int swq = (lr & 7) << 4;   // read-side XOR, (key&7)==(lr&7)

    f32x4 acc[4][2];   // [mt][nt]: rows mt*16+quad*4+r, cols cs*128+wave*32+nt*16+lr
    #pragma unroll
    for (int mt = 0; mt < 4; ++mt)
        #pragma unroll
        for (int nt = 0; nt < 2; ++nt) acc[mt][nt] = (f32x4){0.f, 0.f, 0.f, 0.f};
    float lsum[4] = {0.f, 0.f, 0.f, 0.f};

    {   // prologue: stage K tile 0 into sK[0]
        const char* gk = Kb + stg_go;
        char* lk = (char*)sK[0] + wave * 2048;
        gld_lds16(gk, lk);
        gld_lds16(gk + 2048, lk + 1024);
    }
    __syncthreads();

    int cur = 0;
    for (int kt = 0; kt < 32; ++kt) {
        const int key0 = kt * 64;

        // prefetch V frags for THIS tile (L2 latency hides under S+exp phase)
        bf16x8 vv[2][2];
        #pragma unroll
        for (int nt = 0; nt < 2; ++nt) {
            const unsigned short* vp = Vb + (long)(nt * 16 + lr) * 2048 + key0 + quad * 8;
            vv[nt][0] = *(const bf16x8*)(vp);
            vv[nt][1] = *(const bf16x8*)(vp + 32);
        }

        // async-stage NEXT K tile
        if (kt < 31) {
            const char* gk = Kb + (long)(kt + 1) * 16384 + stg_go;
            char* lk = (char*)sK[cur ^ 1] + wave * 2048;
            gld_lds16(gk, lk);
            gld_lds16(gk + 2048, lk + 1024);
        }

        // S = Q K^T for this wave's 16 rows x all 64 keys
        const char* sKc = (const char*)sK[cur];
        __bf16* sPb = (__bf16*)sP[cur];
        #pragma unroll
        for (int nt = 0; nt < 4; ++nt) {
            const int kb = (nt * 16 + lr) * 128;
            bf16x8 k0 = *(const bf16x8*)(sKc + kb + ((quad * 16) ^ swq));
            bf16x8 k1 = *(const bf16x8*)(sKc + kb + ((quad * 16 + 64) ^ swq));
            f32x4 sv = (f32x4){0.f, 0.f, 0.f, 0.f};
            sv = __builtin_amdgcn_mfma_f32_16x16x32_bf16(qa0, k0, sv, 0, 0, 0);
            sv = __builtin_amdgcn_mfma_f32_16x16x32_bf16(qa1, k1, sv, 0, 0, 0);
            #pragma unroll
            for (int r = 0; r < 4; ++r) {
                const float e = __expf(sv[r]);
                const __bf16 pb = (__bf16)e;       // v_cvt RNE (== manual f2bf)
                lsum[r] += (float)pb;
                sPb[(wave * 16 + quad * 4 + r) * 72 + nt * 16 + lr] = pb;
            }
        }

        __syncthreads();   // publishes sP[cur], drains async sK[cur^1]

        // O += P V  (A-frags of P from LDS, B-frags prefetched)
        const unsigned short* sPc = sP[cur];
        __builtin_amdgcn_s_setprio(1);
        #pragma unroll
        for (int mt = 0; mt < 4; ++mt) {
            const unsigned short* pp = &sPc[(mt * 16 + lr) * 72 + quad * 8];
            bf16x8 p0 = *(const bf16x8*)(pp);
            bf16x8 p1 = *(const bf16x8*)(pp + 32);
            acc[mt][0] = __builtin_amdgcn_mfma_f32_16x16x32_bf16(p0, vv[0][0], acc[mt][0], 0, 0, 0);
            acc[mt][0] = __builtin_amdgcn_mfma_f32_16x16x32_bf16(p1, vv[0][1], acc[mt][0], 0, 0, 0);
            acc[mt][1] = __builtin_amdgcn_mfma_f32_16x16x32_bf16(p0, vv[1][0], acc[mt][1], 0, 0, 0);
            acc[mt][1] = __builtin_amdgcn_mfma_f32_16x16x32_bf16(p1, vv[1][1], acc[mt][1], 0, 0, 0);
        }
        __builtin_amdgcn_s_setprio(0);
        cur ^= 1;
    }

    // row sums -> all waves (via LDS), then O = acc / l
    #pragma unroll
    for (int r = 0; r < 4; ++r) {
        float v = lsum[r];
        v += __shfl_xor(v, 1); v += __shfl_xor(v, 2);
        v += __shfl_xor(v, 4); v += __shfl_xor(v, 8);
        lsum[r] = v;
    }
    if (lr == 0) {
        #pragma unroll
        for (int r = 0; r < 4; ++r) sL[wave * 16 + quad * 4 + r] = lsum[r];
    }
    __syncthreads();

    #pragma unroll
    for (int mt = 0; mt < 4; ++mt) {
        float inv[4];
        #pragma unroll
        for (int r = 0; r < 4; ++r) inv[r] = 1.0f / sL[mt * 16 + quad * 4 + r];
        #pragma unroll
        for (int nt = 0; nt < 2; ++nt) {
            const int col = cs * 128 + wave * 32 + nt * 16 + lr;
            #pragma unroll
            for (int r = 0; r < 4; ++r) {
                const long row = qrow0 + mt * 16 + quad * 4 + r;
                O[row * 512 + col] = f2bf(acc[mt][nt][r] * inv[r]);
            }
        }
    }
}

extern "C" void kernel_launch(void* const* d_in, const int* in_sizes, int n_in,
                              void* d_out, int out_size, void* d_ws, size_t ws_size,
                              hipStream_t stream)
{
    const float* x  = (const float*)d_in[0];
    const float* wq = (const float*)d_in[1];
    const float* bq = (const float*)d_in[2];
    const float* wk = (const float*)d_in[3];
    const float* bk = (const float*)d_in[4];
    const float* wv = (const float*)d_in[5];
    const float* bv = (const float*)d_in[6];
    const float* wo = (const float*)d_in[7];
    const float* bo = (const float*)d_in[8];

    const int W = 512;
    float* out = (float*)d_out;
    dim3 blk(256);
    char* ws = (char*)d_ws;

    const size_t NEED = 56ull << 20;
    if (ws_size < NEED) return;  // zero-output signature

    unsigned short* QK    = (unsigned short*)(ws);                  //  4 MB [16384 x 128] (Q|K)
    unsigned short* VT    = (unsigned short*)(ws + ( 4ull << 20));  // 16 MB [8][512][2048]
    unsigned short* O     = (unsigned short*)(ws + (20ull << 20));  // 16 MB [16384 x 512]
    unsigned short* xb    = (unsigned short*)(ws + (36ull << 20));  // 16 MB [16384 x 512]
    unsigned short* wAllT = (unsigned short*)(ws + (52ull << 20));  // 640 KB [640][512]
    unsigned short* woT   = (unsigned short*)(ws + (53ull << 20));  // 512 KB [512][512]
    float*          ball  = (float*)         (ws + (53ull << 20) + (512ull << 10)); // 2.5 KB

    // pack: x->bf16, bias concat, weights -> bf16 B^T layouts (merged launch)
    pack<<<dim3(2048 + 256), blk, 0, stream>>>(x, xb, bq, bk, bv, ball,
                                               wv, wo, wq, wk, wAllT, woT);

    // Fused QKV projection: [QK | V] = xb @ [wq|wk|wv] + [bq|bk|bv]
    gemm128<true, false, false, false, true><<<dim3(5, 128), blk, 0, stream>>>(
        xb, W, wAllT, W, QK, 128, VT, ball, nullptr, W);

    // Fused attention (no S): O = softmax(Q K^T) V
    flash_attn<<<dim3(1024), blk, 0, stream>>>(QK, VT, O);

    // out = O @ wo + bo + x  (fp32)
    gemm128<true, true, true, false, false><<<dim3(4, 128), blk, 0, stream>>>(
        O, W, woT, W, out, W, nullptr, bo, x, W);
}

// Round 5
// 219.165 us; speedup vs baseline: 1.2076x; 1.0006x over previous
//
#include <hip/hip_runtime.h>

typedef __bf16 bf16x8 __attribute__((ext_vector_type(8)));
typedef float  f32x4  __attribute__((ext_vector_type(4)));

union U8 { uint4 v; unsigned short u[8]; };

static __device__ __forceinline__ float bf2f(unsigned short u) {
    union { unsigned int i; float f; } c; c.i = ((unsigned int)u) << 16; return c.f;
}
static __device__ __forceinline__ unsigned short f2bf(float f) {
    union { float f; unsigned int i; } c; c.f = f;
    unsigned int x = c.i;
    unsigned int r = (x + 0x7FFFu + ((x >> 16) & 1u)) >> 16;  // RNE
    return (unsigned short)r;
}

static __device__ __forceinline__ U8 load8(const float* p) {
    U8 r;
    const float4 a = *(const float4*)p;
    const float4 b = *(const float4*)(p + 4);
    r.u[0] = f2bf(a.x); r.u[1] = f2bf(a.y); r.u[2] = f2bf(a.z); r.u[3] = f2bf(a.w);
    r.u[4] = f2bf(b.x); r.u[5] = f2bf(b.y); r.u[6] = f2bf(b.z); r.u[7] = f2bf(b.w);
    return r;
}

// async global->LDS, 16B per lane. LDS dest must be wave-uniform base (+lane*16 by HW).
static __device__ __forceinline__ void gld_lds16(const void* g, void* l) {
    __builtin_amdgcn_global_load_lds(
        (const __attribute__((address_space(1))) unsigned int*)g,
        (__attribute__((address_space(3))) unsigned int*)l, 16, 0, 0);
}

// ---- merged pack pass: bid<2048: x f32->bf16 + bias concat; else weight transpose ----
// wAllT[640][512] = [wq^T | wk^T | wv^T], woT[512][512], ball[640] = [bq|bk|bv]
__global__ __launch_bounds__(256)
void pack(const float* __restrict__ x, unsigned short* __restrict__ xb,
          const float* __restrict__ bq, const float* __restrict__ bk,
          const float* __restrict__ bv, float* __restrict__ ball,
          const float* __restrict__ wv, const float* __restrict__ wo,
          const float* __restrict__ wq, const float* __restrict__ wk,
          unsigned short* __restrict__ wAllT, unsigned short* __restrict__ woT)
{
    const int bid = blockIdx.x, t = threadIdx.x;
    if (bid < 2048) {
        const long i = ((long)bid * 256 + t) * 16;
        U8 a = load8(x + i);
        U8 b = load8(x + i + 8);
        *(uint4*)(xb + i) = a.v;
        *(uint4*)(xb + i + 8) = b.v;
        if (bid == 0) {
            ball[t]       = t < 64 ? bq[t] : (t < 128 ? bk[t - 64] : bv[t - 128]);
            ball[t + 256] = bv[t + 128];
            if (t < 128) ball[t + 512] = bv[t + 384];
        }
        return;
    }
    // transpose+convert: dst[C][R] = src[R][C]^T, 64x64 tiles
    __shared__ float sT[64][65];
    const int b2 = bid - 2048;
    const int zz = b2 >> 6, rem = b2 & 63;
    const int cx = rem & 7, ry = rem >> 3;
    const float* src; unsigned short* dst; int C;
    if      (zz == 0) { src = wv; dst = wAllT + 128 * 512; C = 512; }
    else if (zz == 1) { src = wo; dst = woT;               C = 512; }
    else if (zz == 2) { src = wq; dst = wAllT;             C = 64;  }
    else              { src = wk; dst = wAllT + 64 * 512;  C = 64;  }
    const int R = 512;
    const int c0 = cx * 64, r0 = ry * 64;
    if (c0 >= C) return;
    #pragma unroll
    for (int k = 0; k < 16; ++k) {
        const int lin = k * 256 + t;
        const int i = lin >> 6, j = lin & 63;
        sT[i][j] = src[(long)(r0 + i) * C + c0 + j];
    }
    __syncthreads();
    #pragma unroll
    for (int k = 0; k < 16; ++k) {
        const int lin = k * 256 + t;
        const int o = lin >> 6, i2 = lin & 63;
        dst[(long)(c0 + o) * R + r0 + i2] = f2bf(sT[i2][o]);
    }
}

// ---- 64x128-tile GEMM: C[M][N] = A[M][K]bf16 @ B^T[N][K]bf16, BK=64 ----
// 4 waves, each 32 rows x 64 cols (2x4 frags). global_load_lds + XOR-swizzle.
// Doubled grid vs 128x128 (QKV: 5/CU, O-proj: 4/CU) for tail/latency hiding.
// MIXED (fused QKV): colBase<128 -> QK interleaved bf16 (ldc=128); colBase>=128 ->
// VT output via LDS-TRANSPOSE epilogue -> COALESCED 16B stores (the old path
// scatter-wrote 16 MB as 2M x 8B strided stores — L2 write amplification).
template<bool BIAS, bool RES, bool OUT_F32, bool MIXED>
__global__ __launch_bounds__(256, 4)
void gemm64(const unsigned short* __restrict__ A, int lda,
            const unsigned short* __restrict__ B, int ldb,
            void* __restrict__ Cp, int ldc,
            void* __restrict__ Cp2,
            const float* __restrict__ bias,
            const float* __restrict__ resid,
            int K)
{
    __shared__ __align__(16) unsigned short sMem[12288];  // 24 KB: sA 8KB | sB 16KB
    unsigned short* sA = sMem;            // [64 rows][64 k], 128 B rows
    unsigned short* sB = sMem + 4096;     // [128 rows][64 k]

    const int t = threadIdx.x, wave = t >> 6, lane = t & 63;
    const int lr = lane & 15, quad = lane >> 4;
    const int rowBase = blockIdx.y * 64, colBase = blockIdx.x * 128;
    const int wm = (wave & 1) * 32, wn = (wave >> 1) * 64;

    const int srow  = lane >> 3;    // 0..7: row within 8-row chunk
    const int sslot = lane & 7;     // 16B slot within 128B row
    const int swz   = (sslot ^ srow) << 4;   // pre-swizzled source (row&7 == srow)

    f32x4 acc[2][4];
    #pragma unroll
    for (int mt = 0; mt < 2; ++mt)
        #pragma unroll
        for (int nt = 0; nt < 4; ++nt) acc[mt][nt] = (f32x4){0.f, 0.f, 0.f, 0.f};

    for (int kt = 0; kt < K; kt += 64) {
        // A: wave stages rows wave*16..+15 (2 chunks of 8 rows)
        #pragma unroll
        for (int is = 0; is < 2; ++is) {
            const int r0 = wave * 16 + is * 8;
            gld_lds16((const char*)A + ((long)(rowBase + r0 + srow) * lda + kt) * 2 + swz,
                      (char*)sA + r0 * 128);
        }
        // B: wave stages rows wave*32..+31 (4 chunks of 8 rows)
        #pragma unroll
        for (int is = 0; is < 4; ++is) {
            const int r0 = wave * 32 + is * 8;
            gld_lds16((const char*)B + ((long)(colBase + r0 + srow) * ldb + kt) * 2 + swz,
                      (char*)sB + r0 * 128);
        }
        __syncthreads();

        #pragma unroll
        for (int ks = 0; ks < 2; ++ks) {
            const int kb = ks * 64 + quad * 16;
            bf16x8 bfr[4];
            #pragma unroll
            for (int nt = 0; nt < 4; ++nt) {
                const int row = wn + nt * 16 + lr;
                bfr[nt] = *(const bf16x8*)((const char*)sB + row * 128 + (kb ^ ((row & 7) << 4)));
            }
            #pragma unroll
            for (int mt = 0; mt < 2; ++mt) {
                const int row = wm + mt * 16 + lr;
                bf16x8 af = *(const bf16x8*)((const char*)sA + row * 128 + (kb ^ ((row & 7) << 4)));
                #pragma unroll
                for (int nt = 0; nt < 4; ++nt)
                    acc[mt][nt] = __builtin_amdgcn_mfma_f32_16x16x32_bf16(af, bfr[nt], acc[mt][nt], 0, 0, 0);
            }
        }
        __syncthreads();
    }

    if (MIXED && colBase >= 128) {
        // ---- VT output: transpose in LDS, then coalesced stores ----
        // sT[col][key] bf16, stride 72 shorts (144 B, 16B-multiple for uint4 reads)
        unsigned short* sT = sMem;   // reuse staging LDS (post final barrier)
        #pragma unroll
        for (int mt = 0; mt < 2; ++mt)
            #pragma unroll
            for (int nt = 0; nt < 4; ++nt) {
                const int row0 = wm + mt * 16 + quad * 4;     // tile-local key
                const int col  = wn + nt * 16 + lr;           // tile-local col
                const float b = BIAS ? bias[colBase + col] : 0.f;
                ushort4 v4;
                v4.x = f2bf(acc[mt][nt][0] + b);
                v4.y = f2bf(acc[mt][nt][1] + b);
                v4.z = f2bf(acc[mt][nt][2] + b);
                v4.w = f2bf(acc[mt][nt][3] + b);
                *(ushort4*)&sT[col * 72 + row0] = v4;
            }
        __syncthreads();
        unsigned short* C2 = (unsigned short*)Cp2;
        const int bat = rowBase >> 11, key0 = rowBase & 2047;
        const long vcol0 = colBase - 128;
        #pragma unroll
        for (int ro = 0; ro < 4; ++ro) {
            const int flat = ro * 256 + t;
            const int col = flat >> 3, ch = flat & 7;
            const uint4 v = *(const uint4*)&sT[col * 72 + ch * 8];
            *(uint4*)&C2[((long)bat * 512 + vcol0 + col) * 2048 + key0 + ch * 8] = v;
        }
        return;
    }

    float* Cf = (float*)Cp;
    unsigned short* Cb = (unsigned short*)Cp;
    #pragma unroll
    for (int mt = 0; mt < 2; ++mt)
        #pragma unroll
        for (int nt = 0; nt < 4; ++nt) {
            const int row0 = rowBase + wm + mt * 16 + quad * 4;
            const int col  = colBase + wn + nt * 16 + lr;
            const float b = BIAS ? bias[col] : 0.f;
            #pragma unroll
            for (int r = 0; r < 4; ++r) {
                const int row = row0 + r;
                float v = acc[mt][nt][r] + b;
                if (RES)     v += resid[(long)row * ldc + col];
                if (OUT_F32) Cf[(long)row * ldc + col] = v;
                else         Cb[(long)row * ldc + col] = f2bf(v);
            }
        }
}

// Fused attention — proven r2/r4 structure (64 Q-rows x 128 V-cols, 1024 blocks,
// 4/CU; each wave computes its own 16 S-rows x 64 keys so the S+exp phase covers
// V/K memory latency). Micro-opts: native (__bf16) cvt (RNE) + s_setprio (T5).
__global__ __launch_bounds__(256, 4)
void flash_attn(const unsigned short* __restrict__ QK,  // [8*2048][128] (Q|K)
                const unsigned short* __restrict__ VT,  // [8][512][2048]
                unsigned short* __restrict__ O)         // [8*2048][512]
{
    __shared__ __align__(16) unsigned short sK[2][64 * 64];   // 2 x 8 KB
    __shared__ __align__(16) unsigned short sP[2][64 * 72];   // 2 x 9 KB
    __shared__ float sL[64];

    const int bid = blockIdx.x;
    const int z  = bid & 7;          // batch -> XCD (round-robin dispatch)
    const int rr = bid >> 3;
    const int cs = rr & 3;           // 128-col split
    const int qt = rr >> 2;          // Q tile (64 rows)

    const int t = threadIdx.x, wave = t >> 6, lane = t & 63;
    const int lr = lane & 15, quad = lane >> 4;

    const long qrow0 = (long)z * 2048 + qt * 64;
    const unsigned short* qp = QK + (qrow0 + wave * 16 + lr) * 128 + quad * 8;
    const bf16x8 qa0 = *(const bf16x8*)(qp);
    const bf16x8 qa1 = *(const bf16x8*)(qp + 32);

    // K rows at QK[z*2048+key][64..127]: 256 B row stride
    const char* Kb = (const char*)(QK + (long)z * 2048 * 128 + 64);
    const unsigned short* Vb = VT + (long)z * 512 * 2048
                                  + ((long)cs * 128 + wave * 32) * 2048;

    // staging: wave stages keys wave*16..+15; PRE-SWIZZLED source, linear LDS
    const long stg_go = (long)(wave * 16 + (lane >> 3)) * 256
                      + (((lane & 7) ^ (lane >> 3)) << 4);
    const int swq = (lr & 7) << 4;   // read-side XOR, (key&7)==(lr&7)

    f32x4 acc[4][2];   // [mt][nt]: rows mt*16+quad*4+r, cols cs*128+wave*32+nt*16+lr
    #pragma unroll
    for (int mt = 0; mt < 4; ++mt)
        #pragma unroll
        for (int nt = 0; nt < 2; ++nt) acc[mt][nt] = (f32x4){0.f, 0.f, 0.f, 0.f};
    float lsum[4] = {0.f, 0.f, 0.f, 0.f};

    {   // prologue: stage K tile 0 into sK[0]
        const char* gk = Kb + stg_go;
        char* lk = (char*)sK[0] + wave * 2048;
        gld_lds16(gk, lk);
        gld_lds16(gk + 2048, lk + 1024);
    }
    __syncthreads();

    int cur = 0;
    for (int kt = 0; kt < 32; ++kt) {
        const int key0 = kt * 64;

        // prefetch V frags for THIS tile (L2 latency hides under S+exp phase)
        bf16x8 vv[2][2];
        #pragma unroll
        for (int nt = 0; nt < 2; ++nt) {
            const unsigned short* vp = Vb + (long)(nt * 16 + lr) * 2048 + key0 + quad * 8;
            vv[nt][0] = *(const bf16x8*)(vp);
            vv[nt][1] = *(const bf16x8*)(vp + 32);
        }

        // async-stage NEXT K tile
        if (kt < 31) {
            const char* gk = Kb + (long)(kt + 1) * 16384 + stg_go;
            char* lk = (char*)sK[cur ^ 1] + wave * 2048;
            gld_lds16(gk, lk);
            gld_lds16(gk + 2048, lk + 1024);
        }

        // S = Q K^T for this wave's 16 rows x all 64 keys
        const char* sKc = (const char*)sK[cur];
        __bf16* sPb = (__bf16*)sP[cur];
        #pragma unroll
        for (int nt = 0; nt < 4; ++nt) {
            const int kb = (nt * 16 + lr) * 128;
            bf16x8 k0 = *(const bf16x8*)(sKc + kb + ((quad * 16) ^ swq));
            bf16x8 k1 = *(const bf16x8*)(sKc + kb + ((quad * 16 + 64) ^ swq));
            f32x4 sv = (f32x4){0.f, 0.f, 0.f, 0.f};
            sv = __builtin_amdgcn_mfma_f32_16x16x32_bf16(qa0, k0, sv, 0, 0, 0);
            sv = __builtin_amdgcn_mfma_f32_16x16x32_bf16(qa1, k1, sv, 0, 0, 0);
            #pragma unroll
            for (int r = 0; r < 4; ++r) {
                const float e = __expf(sv[r]);
                const __bf16 pb = (__bf16)e;       // v_cvt RNE (== manual f2bf)
                lsum[r] += (float)pb;
                sPb[(wave * 16 + quad * 4 + r) * 72 + nt * 16 + lr] = pb;
            }
        }

        __syncthreads();   // publishes sP[cur], drains async sK[cur^1]

        // O += P V  (A-frags of P from LDS, B-frags prefetched)
        const unsigned short* sPc = sP[cur];
        __builtin_amdgcn_s_setprio(1);
        #pragma unroll
        for (int mt = 0; mt < 4; ++mt) {
            const unsigned short* pp = &sPc[(mt * 16 + lr) * 72 + quad * 8];
            bf16x8 p0 = *(const bf16x8*)(pp);
            bf16x8 p1 = *(const bf16x8*)(pp + 32);
            acc[mt][0] = __builtin_amdgcn_mfma_f32_16x16x32_bf16(p0, vv[0][0], acc[mt][0], 0, 0, 0);
            acc[mt][0] = __builtin_amdgcn_mfma_f32_16x16x32_bf16(p1, vv[0][1], acc[mt][0], 0, 0, 0);
            acc[mt][1] = __builtin_amdgcn_mfma_f32_16x16x32_bf16(p0, vv[1][0], acc[mt][1], 0, 0, 0);
            acc[mt][1] = __builtin_amdgcn_mfma_f32_16x16x32_bf16(p1, vv[1][1], acc[mt][1], 0, 0, 0);
        }
        __builtin_amdgcn_s_setprio(0);
        cur ^= 1;
    }

    // row sums -> all waves (via LDS), then O = acc / l
    #pragma unroll
    for (int r = 0; r < 4; ++r) {
        float v = lsum[r];
        v += __shfl_xor(v, 1); v += __shfl_xor(v, 2);
        v += __shfl_xor(v, 4); v += __shfl_xor(v, 8);
        lsum[r] = v;
    }
    if (lr == 0) {
        #pragma unroll
        for (int r = 0; r < 4; ++r) sL[wave * 16 + quad * 4 + r] = lsum[r];
    }
    __syncthreads();

    #pragma unroll
    for (int mt = 0; mt < 4; ++mt) {
        float inv[4];
        #pragma unroll
        for (int r = 0; r < 4; ++r) inv[r] = 1.0f / sL[mt * 16 + quad * 4 + r];
        #pragma unroll
        for (int nt = 0; nt < 2; ++nt) {
            const int col = cs * 128 + wave * 32 + nt * 16 + lr;
            #pragma unroll
            for (int r = 0; r < 4; ++r) {
                const long row = qrow0 + mt * 16 + quad * 4 + r;
                O[row * 512 + col] = f2bf(acc[mt][nt][r] * inv[r]);
            }
        }
    }
}

extern "C" void kernel_launch(void* const* d_in, const int* in_sizes, int n_in,
                              void* d_out, int out_size, void* d_ws, size_t ws_size,
                              hipStream_t stream)
{
    const float* x  = (const float*)d_in[0];
    const float* wq = (const float*)d_in[1];
    const float* bq = (const float*)d_in[2];
    const float* wk = (const float*)d_in[3];
    const float* bk = (const float*)d_in[4];
    const float* wv = (const float*)d_in[5];
    const float* bv = (const float*)d_in[6];
    const float* wo = (const float*)d_in[7];
    const float* bo = (const float*)d_in[8];

    const int W = 512;
    float* out = (float*)d_out;
    dim3 blk(256);
    char* ws = (char*)d_ws;

    const size_t NEED = 56ull << 20;
    if (ws_size < NEED) return;  // zero-output signature

    unsigned short* QK    = (unsigned short*)(ws);                  //  4 MB [16384 x 128] (Q|K)
    unsigned short* VT    = (unsigned short*)(ws + ( 4ull << 20));  // 16 MB [8][512][2048]
    unsigned short* O     = (unsigned short*)(ws + (20ull << 20));  // 16 MB [16384 x 512]
    unsigned short* xb    = (unsigned short*)(ws + (36ull << 20));  // 16 MB [16384 x 512]
    unsigned short* wAllT = (unsigned short*)(ws + (52ull << 20));  // 640 KB [640][512]
    unsigned short* woT   = (unsigned short*)(ws + (53ull << 20));  // 512 KB [512][512]
    float*          ball  = (float*)         (ws + (53ull << 20) + (512ull << 10)); // 2.5 KB

    // pack: x->bf16, bias concat, weights -> bf16 B^T layouts (merged launch)
    pack<<<dim3(2048 + 256), blk, 0, stream>>>(x, xb, bq, bk, bv, ball,
                                               wv, wo, wq, wk, wAllT, woT);

    // Fused QKV projection: [QK | V] = xb @ [wq|wk|wv] + [bq|bk|bv]
    // 64-row tiles: grid (5,256) = 1280 blocks ~ 5/CU
    gemm64<true, false, false, true><<<dim3(5, 256), blk, 0, stream>>>(
        xb, W, wAllT, W, QK, 128, VT, ball, nullptr, W);

    // Fused attention (no S): O = softmax(Q K^T) V
    flash_attn<<<dim3(1024), blk, 0, stream>>>(QK, VT, O);

    // out = O @ wo + bo + x  (fp32); grid (4,256) = 1024 blocks = 4/CU
    gemm64<true, true, true, false><<<dim3(4, 256), blk, 0, stream>>>(
        O, W, woT, W, out, W, nullptr, bo, x, W);
}

// Round 6
// 212.702 us; speedup vs baseline: 1.2443x; 1.0304x over previous
//
#include <hip/hip_runtime.h>

typedef __bf16 bf16x8 __attribute__((ext_vector_type(8)));
typedef float  f32x4  __attribute__((ext_vector_type(4)));

union U8 { uint4 v; unsigned short u[8]; };

static __device__ __forceinline__ float bf2f(unsigned short u) {
    union { unsigned int i; float f; } c; c.i = ((unsigned int)u) << 16; return c.f;
}
static __device__ __forceinline__ unsigned short f2bf(float f) {
    union { float f; unsigned int i; } c; c.f = f;
    unsigned int x = c.i;
    unsigned int r = (x + 0x7FFFu + ((x >> 16) & 1u)) >> 16;  // RNE
    return (unsigned short)r;
}

static __device__ __forceinline__ U8 load8(const float* p) {
    U8 r;
    const float4 a = *(const float4*)p;
    const float4 b = *(const float4*)(p + 4);
    r.u[0] = f2bf(a.x); r.u[1] = f2bf(a.y); r.u[2] = f2bf(a.z); r.u[3] = f2bf(a.w);
    r.u[4] = f2bf(b.x); r.u[5] = f2bf(b.y); r.u[6] = f2bf(b.z); r.u[7] = f2bf(b.w);
    return r;
}

// async global->LDS, 16B per lane. LDS dest must be wave-uniform base (+lane*16 by HW).
static __device__ __forceinline__ void gld_lds16(const void* g, void* l) {
    __builtin_amdgcn_global_load_lds(
        (const __attribute__((address_space(1))) unsigned int*)g,
        (__attribute__((address_space(3))) unsigned int*)l, 16, 0, 0);
}

// ---- merged pack pass: bid<2048: x f32->bf16 + bias concat; else weight transpose ----
// wAllT[640][512] = [wq^T | wk^T | wv^T], woT[512][512], ball[640] = [bq|bk|bv]
__global__ __launch_bounds__(256)
void pack(const float* __restrict__ x, unsigned short* __restrict__ xb,
          const float* __restrict__ bq, const float* __restrict__ bk,
          const float* __restrict__ bv, float* __restrict__ ball,
          const float* __restrict__ wv, const float* __restrict__ wo,
          const float* __restrict__ wq, const float* __restrict__ wk,
          unsigned short* __restrict__ wAllT, unsigned short* __restrict__ woT)
{
    const int bid = blockIdx.x, t = threadIdx.x;
    if (bid < 2048) {
        const long i = ((long)bid * 256 + t) * 16;
        U8 a = load8(x + i);
        U8 b = load8(x + i + 8);
        *(uint4*)(xb + i) = a.v;
        *(uint4*)(xb + i + 8) = b.v;
        if (bid == 0) {
            ball[t]       = t < 64 ? bq[t] : (t < 128 ? bk[t - 64] : bv[t - 128]);
            ball[t + 256] = bv[t + 128];
            if (t < 128) ball[t + 512] = bv[t + 384];
        }
        return;
    }
    // transpose+convert: dst[C][R] = src[R][C]^T, 64x64 tiles
    __shared__ float sT[64][65];
    const int b2 = bid - 2048;
    const int zz = b2 >> 6, rem = b2 & 63;
    const int cx = rem & 7, ry = rem >> 3;
    const float* src; unsigned short* dst; int C;
    if      (zz == 0) { src = wv; dst = wAllT + 128 * 512; C = 512; }
    else if (zz == 1) { src = wo; dst = woT;               C = 512; }
    else if (zz == 2) { src = wq; dst = wAllT;             C = 64;  }
    else              { src = wk; dst = wAllT + 64 * 512;  C = 64;  }
    const int R = 512;
    const int c0 = cx * 64, r0 = ry * 64;
    if (c0 >= C) return;
    #pragma unroll
    for (int k = 0; k < 16; ++k) {
        const int lin = k * 256 + t;
        const int i = lin >> 6, j = lin & 63;
        sT[i][j] = src[(long)(r0 + i) * C + c0 + j];
    }
    __syncthreads();
    #pragma unroll
    for (int k = 0; k < 16; ++k) {
        const int lin = k * 256 + t;
        const int o = lin >> 6, i2 = lin & 63;
        dst[(long)(c0 + o) * R + r0 + i2] = f2bf(sT[i2][o]);
    }
}

// ---- 64x128-tile GEMM, BK=64, DOUBLE-BUFFERED 1-barrier K-loop + XCD swizzle ----
// C[M][N] = A[M][K]bf16 @ B^T[N][K]bf16. 4 waves, each 32 rows x 64 cols.
// XCD swizzle (T1): flat grid NCOL*256, sw=(bid&7)*cpx+(bid>>3), rows-major per
// XCD chunk -> each XCD owns 32 row-panels x all col-blocks -> A panel fetched
// from HBM once per XCD (was xNCOL: consecutive flat ids = same row, different
// XCD). 1-barrier dbuf (flash_attn's proven pattern): stage tile k+1 async into
// buf^1 BEFORE computing buf; the per-iter barrier's vmcnt(0) drain overlaps MFMA.
// MIXED (fused QKV): colBase<128 -> QK interleaved (ldc=128); else VT via
// LDS-transpose epilogue -> coalesced 16B stores.
template<bool BIAS, bool RES, bool OUT_F32, bool MIXED, int NCOL>
__global__ __launch_bounds__(256, 3)
void gemm64(const unsigned short* __restrict__ A, int lda,
            const unsigned short* __restrict__ B, int ldb,
            void* __restrict__ Cp, int ldc,
            void* __restrict__ Cp2,
            const float* __restrict__ bias,
            const float* __restrict__ resid,
            int K)
{
    __shared__ __align__(16) unsigned short sMem[2][12288];  // 2 x 24 KB (sA 8K | sB 16K)

    const int t = threadIdx.x, wave = t >> 6, lane = t & 63;
    const int lr = lane & 15, quad = lane >> 4;

    // bijective XCD swizzle: nwg = NCOL*256, cpx = NCOL*32 (nwg%8==0)
    const int bid = blockIdx.x;
    const int sw  = (bid & 7) * (NCOL * 32) + (bid >> 3);
    const int rowBase = (sw / NCOL) * 64;
    const int colBase = (sw % NCOL) * 128;
    const int wm = (wave & 1) * 32, wn = (wave >> 1) * 64;

    const int srow  = lane >> 3;    // 0..7: row within 8-row chunk
    const int sslot = lane & 7;     // 16B slot within 128B row
    const int swz   = (sslot ^ srow) << 4;   // pre-swizzled source (row&7 == srow)

    f32x4 acc[2][4];
    #pragma unroll
    for (int mt = 0; mt < 2; ++mt)
        #pragma unroll
        for (int nt = 0; nt < 4; ++nt) acc[mt][nt] = (f32x4){0.f, 0.f, 0.f, 0.f};

    // async-stage one 64x64 A-tile + 128x64 B-tile into sMem[buf]
    auto STAGE = [&](int buf, int kt) {
        unsigned short* sA = sMem[buf];
        unsigned short* sB = sMem[buf] + 4096;
        #pragma unroll
        for (int is = 0; is < 2; ++is) {
            const int r0 = wave * 16 + is * 8;
            gld_lds16((const char*)A + ((long)(rowBase + r0 + srow) * lda + kt) * 2 + swz,
                      (char*)sA + r0 * 128);
        }
        #pragma unroll
        for (int is = 0; is < 4; ++is) {
            const int r0 = wave * 32 + is * 8;
            gld_lds16((const char*)B + ((long)(colBase + r0 + srow) * ldb + kt) * 2 + swz,
                      (char*)sB + r0 * 128);
        }
    };

    STAGE(0, 0);
    __syncthreads();   // tile 0 resident

    int cur = 0;
    for (int kt = 0; kt < K; kt += 64) {
        if (kt + 64 < K) STAGE(cur ^ 1, kt + 64);   // issue next tile first

        const unsigned short* sA = sMem[cur];
        const unsigned short* sB = sMem[cur] + 4096;
        #pragma unroll
        for (int ks = 0; ks < 2; ++ks) {
            const int kb = ks * 64 + quad * 16;
            bf16x8 bfr[4];
            #pragma unroll
            for (int nt = 0; nt < 4; ++nt) {
                const int row = wn + nt * 16 + lr;
                bfr[nt] = *(const bf16x8*)((const char*)sB + row * 128 + (kb ^ ((row & 7) << 4)));
            }
            #pragma unroll
            for (int mt = 0; mt < 2; ++mt) {
                const int row = wm + mt * 16 + lr;
                bf16x8 af = *(const bf16x8*)((const char*)sA + row * 128 + (kb ^ ((row & 7) << 4)));
                #pragma unroll
                for (int nt = 0; nt < 4; ++nt)
                    acc[mt][nt] = __builtin_amdgcn_mfma_f32_16x16x32_bf16(af, bfr[nt], acc[mt][nt], 0, 0, 0);
            }
        }
        __syncthreads();   // publishes next tile, reuse of old buffer is post-barrier
        cur ^= 1;
    }

    if (MIXED && colBase >= 128) {
        // ---- VT output: transpose in LDS, then coalesced stores ----
        unsigned short* sT = sMem[0];   // reuse staging LDS (post final barrier)
        #pragma unroll
        for (int mt = 0; mt < 2; ++mt)
            #pragma unroll
            for (int nt = 0; nt < 4; ++nt) {
                const int row0 = wm + mt * 16 + quad * 4;     // tile-local key
                const int col  = wn + nt * 16 + lr;           // tile-local col
                const float b = BIAS ? bias[colBase + col] : 0.f;
                ushort4 v4;
                v4.x = f2bf(acc[mt][nt][0] + b);
                v4.y = f2bf(acc[mt][nt][1] + b);
                v4.z = f2bf(acc[mt][nt][2] + b);
                v4.w = f2bf(acc[mt][nt][3] + b);
                *(ushort4*)&sT[col * 72 + row0] = v4;
            }
        __syncthreads();
        unsigned short* C2 = (unsigned short*)Cp2;
        const int bat = rowBase >> 11, key0 = rowBase & 2047;
        const long vcol0 = colBase - 128;
        #pragma unroll
        for (int ro = 0; ro < 4; ++ro) {
            const int flat = ro * 256 + t;
            const int col = flat >> 3, ch = flat & 7;
            const uint4 v = *(const uint4*)&sT[col * 72 + ch * 8];
            *(uint4*)&C2[((long)bat * 512 + vcol0 + col) * 2048 + key0 + ch * 8] = v;
        }
        return;
    }

    float* Cf = (float*)Cp;
    unsigned short* Cb = (unsigned short*)Cp;
    #pragma unroll
    for (int mt = 0; mt < 2; ++mt)
        #pragma unroll
        for (int nt = 0; nt < 4; ++nt) {
            const int row0 = rowBase + wm + mt * 16 + quad * 4;
            const int col  = colBase + wn + nt * 16 + lr;
            const float b = BIAS ? bias[col] : 0.f;
            #pragma unroll
            for (int r = 0; r < 4; ++r) {
                const int row = row0 + r;
                float v = acc[mt][nt][r] + b;
                if (RES)     v += resid[(long)row * ldc + col];
                if (OUT_F32) Cf[(long)row * ldc + col] = v;
                else         Cb[(long)row * ldc + col] = f2bf(v);
            }
        }
}

// Fused attention — proven r2/r4 structure (64 Q-rows x 128 V-cols, 1024 blocks,
// 4/CU; each wave computes its own 16 S-rows x 64 keys so the S+exp phase covers
// V/K memory latency). Micro-opts: native (__bf16) cvt (RNE) + s_setprio (T5).
// BYTE-IDENTICAL to r5 (88 us) for attribution.
__global__ __launch_bounds__(256, 4)
void flash_attn(const unsigned short* __restrict__ QK,  // [8*2048][128] (Q|K)
                const unsigned short* __restrict__ VT,  // [8][512][2048]
                unsigned short* __restrict__ O)         // [8*2048][512]
{
    __shared__ __align__(16) unsigned short sK[2][64 * 64];   // 2 x 8 KB
    __shared__ __align__(16) unsigned short sP[2][64 * 72];   // 2 x 9 KB
    __shared__ float sL[64];

    const int bid = blockIdx.x;
    const int z  = bid & 7;          // batch -> XCD (round-robin dispatch)
    const int rr = bid >> 3;
    const int cs = rr & 3;           // 128-col split
    const int qt = rr >> 2;          // Q tile (64 rows)

    const int t = threadIdx.x, wave = t >> 6, lane = t & 63;
    const int lr = lane & 15, quad = lane >> 4;

    const long qrow0 = (long)z * 2048 + qt * 64;
    const unsigned short* qp = QK + (qrow0 + wave * 16 + lr) * 128 + quad * 8;
    const bf16x8 qa0 = *(const bf16x8*)(qp);
    const bf16x8 qa1 = *(const bf16x8*)(qp + 32);

    // K rows at QK[z*2048+key][64..127]: 256 B row stride
    const char* Kb = (const char*)(QK + (long)z * 2048 * 128 + 64);
    const unsigned short* Vb = VT + (long)z * 512 * 2048
                                  + ((long)cs * 128 + wave * 32) * 2048;

    // staging: wave stages keys wave*16..+15; PRE-SWIZZLED source, linear LDS
    const long stg_go = (long)(wave * 16 + (lane >> 3)) * 256
                      + (((lane & 7) ^ (lane >> 3)) << 4);
    const int swq = (lr & 7) << 4;   // read-side XOR, (key&7)==(lr&7)

    f32x4 acc[4][2];   // [mt][nt]: rows mt*16+quad*4+r, cols cs*128+wave*32+nt*16+lr
    #pragma unroll
    for (int mt = 0; mt < 4; ++mt)
        #pragma unroll
        for (int nt = 0; nt < 2; ++nt) acc[mt][nt] = (f32x4){0.f, 0.f, 0.f, 0.f};
    float lsum[4] = {0.f, 0.f, 0.f, 0.f};

    {   // prologue: stage K tile 0 into sK[0]
        const char* gk = Kb + stg_go;
        char* lk = (char*)sK[0] + wave * 2048;
        gld_lds16(gk, lk);
        gld_lds16(gk + 2048, lk + 1024);
    }
    __syncthreads();

    int cur = 0;
    for (int kt = 0; kt < 32; ++kt) {
        const int key0 = kt * 64;

        // prefetch V frags for THIS tile (L2 latency hides under S+exp phase)
        bf16x8 vv[2][2];
        #pragma unroll
        for (int nt = 0; nt < 2; ++nt) {
            const unsigned short* vp = Vb + (long)(nt * 16 + lr) * 2048 + key0 + quad * 8;
            vv[nt][0] = *(const bf16x8*)(vp);
            vv[nt][1] = *(const bf16x8*)(vp + 32);
        }

        // async-stage NEXT K tile
        if (kt < 31) {
            const char* gk = Kb + (long)(kt + 1) * 16384 + stg_go;
            char* lk = (char*)sK[cur ^ 1] + wave * 2048;
            gld_lds16(gk, lk);
            gld_lds16(gk + 2048, lk + 1024);
        }

        // S = Q K^T for this wave's 16 rows x all 64 keys
        const char* sKc = (const char*)sK[cur];
        __bf16* sPb = (__bf16*)sP[cur];
        #pragma unroll
        for (int nt = 0; nt < 4; ++nt) {
            const int kb = (nt * 16 + lr) * 128;
            bf16x8 k0 = *(const bf16x8*)(sKc + kb + ((quad * 16) ^ swq));
            bf16x8 k1 = *(const bf16x8*)(sKc + kb + ((quad * 16 + 64) ^ swq));
            f32x4 sv = (f32x4){0.f, 0.f, 0.f, 0.f};
            sv = __builtin_amdgcn_mfma_f32_16x16x32_bf16(qa0, k0, sv, 0, 0, 0);
            sv = __builtin_amdgcn_mfma_f32_16x16x32_bf16(qa1, k1, sv, 0, 0, 0);
            #pragma unroll
            for (int r = 0; r < 4; ++r) {
                const float e = __expf(sv[r]);
                const __bf16 pb = (__bf16)e;       // v_cvt RNE (== manual f2bf)
                lsum[r] += (float)pb;
                sPb[(wave * 16 + quad * 4 + r) * 72 + nt * 16 + lr] = pb;
            }
        }

        __syncthreads();   // publishes sP[cur], drains async sK[cur^1]

        // O += P V  (A-frags of P from LDS, B-frags prefetched)
        const unsigned short* sPc = sP[cur];
        __builtin_amdgcn_s_setprio(1);
        #pragma unroll
        for (int mt = 0; mt < 4; ++mt) {
            const unsigned short* pp = &sPc[(mt * 16 + lr) * 72 + quad * 8];
            bf16x8 p0 = *(const bf16x8*)(pp);
            bf16x8 p1 = *(const bf16x8*)(pp + 32);
            acc[mt][0] = __builtin_amdgcn_mfma_f32_16x16x32_bf16(p0, vv[0][0], acc[mt][0], 0, 0, 0);
            acc[mt][0] = __builtin_amdgcn_mfma_f32_16x16x32_bf16(p1, vv[0][1], acc[mt][0], 0, 0, 0);
            acc[mt][1] = __builtin_amdgcn_mfma_f32_16x16x32_bf16(p0, vv[1][0], acc[mt][1], 0, 0, 0);
            acc[mt][1] = __builtin_amdgcn_mfma_f32_16x16x32_bf16(p1, vv[1][1], acc[mt][1], 0, 0, 0);
        }
        __builtin_amdgcn_s_setprio(0);
        cur ^= 1;
    }

    // row sums -> all waves (via LDS), then O = acc / l
    #pragma unroll
    for (int r = 0; r < 4; ++r) {
        float v = lsum[r];
        v += __shfl_xor(v, 1); v += __shfl_xor(v, 2);
        v += __shfl_xor(v, 4); v += __shfl_xor(v, 8);
        lsum[r] = v;
    }
    if (lr == 0) {
        #pragma unroll
        for (int r = 0; r < 4; ++r) sL[wave * 16 + quad * 4 + r] = lsum[r];
    }
    __syncthreads();

    #pragma unroll
    for (int mt = 0; mt < 4; ++mt) {
        float inv[4];
        #pragma unroll
        for (int r = 0; r < 4; ++r) inv[r] = 1.0f / sL[mt * 16 + quad * 4 + r];
        #pragma unroll
        for (int nt = 0; nt < 2; ++nt) {
            const int col = cs * 128 + wave * 32 + nt * 16 + lr;
            #pragma unroll
            for (int r = 0; r < 4; ++r) {
                const long row = qrow0 + mt * 16 + quad * 4 + r;
                O[row * 512 + col] = f2bf(acc[mt][nt][r] * inv[r]);
            }
        }
    }
}

extern "C" void kernel_launch(void* const* d_in, const int* in_sizes, int n_in,
                              void* d_out, int out_size, void* d_ws, size_t ws_size,
                              hipStream_t stream)
{
    const float* x  = (const float*)d_in[0];
    const float* wq = (const float*)d_in[1];
    const float* bq = (const float*)d_in[2];
    const float* wk = (const float*)d_in[3];
    const float* bk = (const float*)d_in[4];
    const float* wv = (const float*)d_in[5];
    const float* bv = (const float*)d_in[6];
    const float* wo = (const float*)d_in[7];
    const float* bo = (const float*)d_in[8];

    const int W = 512;
    float* out = (float*)d_out;
    dim3 blk(256);
    char* ws = (char*)d_ws;

    const size_t NEED = 56ull << 20;
    if (ws_size < NEED) return;  // zero-output signature

    unsigned short* QK    = (unsigned short*)(ws);                  //  4 MB [16384 x 128] (Q|K)
    unsigned short* VT    = (unsigned short*)(ws + ( 4ull << 20));  // 16 MB [8][512][2048]
    unsigned short* O     = (unsigned short*)(ws + (20ull << 20));  // 16 MB [16384 x 512]
    unsigned short* xb    = (unsigned short*)(ws + (36ull << 20));  // 16 MB [16384 x 512]
    unsigned short* wAllT = (unsigned short*)(ws + (52ull << 20));  // 640 KB [640][512]
    unsigned short* woT   = (unsigned short*)(ws + (53ull << 20));  // 512 KB [512][512]
    float*          ball  = (float*)         (ws + (53ull << 20) + (512ull << 10)); // 2.5 KB

    // pack: x->bf16, bias concat, weights -> bf16 B^T layouts (merged launch)
    pack<<<dim3(2048 + 256), blk, 0, stream>>>(x, xb, bq, bk, bv, ball,
                                               wv, wo, wq, wk, wAllT, woT);

    // Fused QKV projection: [QK | V] = xb @ [wq|wk|wv] + [bq|bk|bv]
    // flat grid 5*256 = 1280 blocks; XCD-swizzled inside kernel
    gemm64<true, false, false, true, 5><<<dim3(1280), blk, 0, stream>>>(
        xb, W, wAllT, W, QK, 128, VT, ball, nullptr, W);

    // Fused attention (no S): O = softmax(Q K^T) V
    flash_attn<<<dim3(1024), blk, 0, stream>>>(QK, VT, O);

    // out = O @ wo + bo + x  (fp32); flat grid 4*256 = 1024 blocks
    gemm64<true, true, true, false, 4><<<dim3(1024), blk, 0, stream>>>(
        O, W, woT, W, out, W, nullptr, bo, x, W);
}

// Round 7
// 200.449 us; speedup vs baseline: 1.3204x; 1.0611x over previous
//
#include <hip/hip_runtime.h>

typedef __bf16 bf16x8 __attribute__((ext_vector_type(8)));
typedef float  f32x4  __attribute__((ext_vector_type(4)));

union U8 { uint4 v; unsigned short u[8]; };

static __device__ __forceinline__ float bf2f(unsigned short u) {
    union { unsigned int i; float f; } c; c.i = ((unsigned int)u) << 16; return c.f;
}
static __device__ __forceinline__ unsigned short f2bf(float f) {
    union { float f; unsigned int i; } c; c.f = f;
    unsigned int x = c.i;
    unsigned int r = (x + 0x7FFFu + ((x >> 16) & 1u)) >> 16;  // RNE
    return (unsigned short)r;
}

static __device__ __forceinline__ U8 load8(const float* p) {
    U8 r;
    const float4 a = *(const float4*)p;
    const float4 b = *(const float4*)(p + 4);
    r.u[0] = f2bf(a.x); r.u[1] = f2bf(a.y); r.u[2] = f2bf(a.z); r.u[3] = f2bf(a.w);
    r.u[4] = f2bf(b.x); r.u[5] = f2bf(b.y); r.u[6] = f2bf(b.z); r.u[7] = f2bf(b.w);
    return r;
}

// async global->LDS, 16B per lane. LDS dest must be wave-uniform base (+lane*16 by HW).
static __device__ __forceinline__ void gld_lds16(const void* g, void* l) {
    __builtin_amdgcn_global_load_lds(
        (const __attribute__((address_space(1))) unsigned int*)g,
        (__attribute__((address_space(3))) unsigned int*)l, 16, 0, 0);
}

// ---- merged pack pass: bid<2048: x f32->bf16 + bias concat; else weight transpose ----
// wAllT[640][512] = [wq^T | wk^T | wv^T], woT[512][512], ball[640] = [bq|bk|bv]
__global__ __launch_bounds__(256)
void pack(const float* __restrict__ x, unsigned short* __restrict__ xb,
          const float* __restrict__ bq, const float* __restrict__ bk,
          const float* __restrict__ bv, float* __restrict__ ball,
          const float* __restrict__ wv, const float* __restrict__ wo,
          const float* __restrict__ wq, const float* __restrict__ wk,
          unsigned short* __restrict__ wAllT, unsigned short* __restrict__ woT)
{
    const int bid = blockIdx.x, t = threadIdx.x;
    if (bid < 2048) {
        const long i = ((long)bid * 256 + t) * 16;
        U8 a = load8(x + i);
        U8 b = load8(x + i + 8);
        *(uint4*)(xb + i) = a.v;
        *(uint4*)(xb + i + 8) = b.v;
        if (bid == 0) {
            ball[t]       = t < 64 ? bq[t] : (t < 128 ? bk[t - 64] : bv[t - 128]);
            ball[t + 256] = bv[t + 128];
            if (t < 128) ball[t + 512] = bv[t + 384];
        }
        return;
    }
    // transpose+convert: dst[C][R] = src[R][C]^T, 64x64 tiles
    __shared__ float sT[64][65];
    const int b2 = bid - 2048;
    const int zz = b2 >> 6, rem = b2 & 63;
    const int cx = rem & 7, ry = rem >> 3;
    const float* src; unsigned short* dst; int C;
    if      (zz == 0) { src = wv; dst = wAllT + 128 * 512; C = 512; }
    else if (zz == 1) { src = wo; dst = woT;               C = 512; }
    else if (zz == 2) { src = wq; dst = wAllT;             C = 64;  }
    else              { src = wk; dst = wAllT + 64 * 512;  C = 64;  }
    const int R = 512;
    const int c0 = cx * 64, r0 = ry * 64;
    if (c0 >= C) return;
    #pragma unroll
    for (int k = 0; k < 16; ++k) {
        const int lin = k * 256 + t;
        const int i = lin >> 6, j = lin & 63;
        sT[i][j] = src[(long)(r0 + i) * C + c0 + j];
    }
    __syncthreads();
    #pragma unroll
    for (int k = 0; k < 16; ++k) {
        const int lin = k * 256 + t;
        const int o = lin >> 6, i2 = lin & 63;
        dst[(long)(c0 + o) * R + r0 + i2] = f2bf(sT[i2][o]);
    }
}

// ---- 64x128-tile GEMM, BK=64, DOUBLE-BUFFERED 1-barrier K-loop + XCD swizzle ----
// (unchanged from r6, which measured −6.5 us vs r5)
template<bool BIAS, bool RES, bool OUT_F32, bool MIXED, int NCOL>
__global__ __launch_bounds__(256, 3)
void gemm64(const unsigned short* __restrict__ A, int lda,
            const unsigned short* __restrict__ B, int ldb,
            void* __restrict__ Cp, int ldc,
            void* __restrict__ Cp2,
            const float* __restrict__ bias,
            const float* __restrict__ resid,
            int K)
{
    __shared__ __align__(16) unsigned short sMem[2][12288];  // 2 x 24 KB (sA 8K | sB 16K)

    const int t = threadIdx.x, wave = t >> 6, lane = t & 63;
    const int lr = lane & 15, quad = lane >> 4;

    // bijective XCD swizzle: nwg = NCOL*256, cpx = NCOL*32 (nwg%8==0)
    const int bid = blockIdx.x;
    const int sw  = (bid & 7) * (NCOL * 32) + (bid >> 3);
    const int rowBase = (sw / NCOL) * 64;
    const int colBase = (sw % NCOL) * 128;
    const int wm = (wave & 1) * 32, wn = (wave >> 1) * 64;

    const int srow  = lane >> 3;
    const int sslot = lane & 7;
    const int swz   = (sslot ^ srow) << 4;   // pre-swizzled source (row&7 == srow)

    f32x4 acc[2][4];
    #pragma unroll
    for (int mt = 0; mt < 2; ++mt)
        #pragma unroll
        for (int nt = 0; nt < 4; ++nt) acc[mt][nt] = (f32x4){0.f, 0.f, 0.f, 0.f};

    auto STAGE = [&](int buf, int kt) {
        unsigned short* sA = sMem[buf];
        unsigned short* sB = sMem[buf] + 4096;
        #pragma unroll
        for (int is = 0; is < 2; ++is) {
            const int r0 = wave * 16 + is * 8;
            gld_lds16((const char*)A + ((long)(rowBase + r0 + srow) * lda + kt) * 2 + swz,
                      (char*)sA + r0 * 128);
        }
        #pragma unroll
        for (int is = 0; is < 4; ++is) {
            const int r0 = wave * 32 + is * 8;
            gld_lds16((const char*)B + ((long)(colBase + r0 + srow) * ldb + kt) * 2 + swz,
                      (char*)sB + r0 * 128);
        }
    };

    STAGE(0, 0);
    __syncthreads();

    int cur = 0;
    for (int kt = 0; kt < K; kt += 64) {
        if (kt + 64 < K) STAGE(cur ^ 1, kt + 64);

        const unsigned short* sA = sMem[cur];
        const unsigned short* sB = sMem[cur] + 4096;
        #pragma unroll
        for (int ks = 0; ks < 2; ++ks) {
            const int kb = ks * 64 + quad * 16;
            bf16x8 bfr[4];
            #pragma unroll
            for (int nt = 0; nt < 4; ++nt) {
                const int row = wn + nt * 16 + lr;
                bfr[nt] = *(const bf16x8*)((const char*)sB + row * 128 + (kb ^ ((row & 7) << 4)));
            }
            #pragma unroll
            for (int mt = 0; mt < 2; ++mt) {
                const int row = wm + mt * 16 + lr;
                bf16x8 af = *(const bf16x8*)((const char*)sA + row * 128 + (kb ^ ((row & 7) << 4)));
                #pragma unroll
                for (int nt = 0; nt < 4; ++nt)
                    acc[mt][nt] = __builtin_amdgcn_mfma_f32_16x16x32_bf16(af, bfr[nt], acc[mt][nt], 0, 0, 0);
            }
        }
        __syncthreads();
        cur ^= 1;
    }

    if (MIXED && colBase >= 128) {
        unsigned short* sT = sMem[0];
        #pragma unroll
        for (int mt = 0; mt < 2; ++mt)
            #pragma unroll
            for (int nt = 0; nt < 4; ++nt) {
                const int row0 = wm + mt * 16 + quad * 4;
                const int col  = wn + nt * 16 + lr;
                const float b = BIAS ? bias[colBase + col] : 0.f;
                ushort4 v4;
                v4.x = f2bf(acc[mt][nt][0] + b);
                v4.y = f2bf(acc[mt][nt][1] + b);
                v4.z = f2bf(acc[mt][nt][2] + b);
                v4.w = f2bf(acc[mt][nt][3] + b);
                *(ushort4*)&sT[col * 72 + row0] = v4;
            }
        __syncthreads();
        unsigned short* C2 = (unsigned short*)Cp2;
        const int bat = rowBase >> 11, key0 = rowBase & 2047;
        const long vcol0 = colBase - 128;
        #pragma unroll
        for (int ro = 0; ro < 4; ++ro) {
            const int flat = ro * 256 + t;
            const int col = flat >> 3, ch = flat & 7;
            const uint4 v = *(const uint4*)&sT[col * 72 + ch * 8];
            *(uint4*)&C2[((long)bat * 512 + vcol0 + col) * 2048 + key0 + ch * 8] = v;
        }
        return;
    }

    float* Cf = (float*)Cp;
    unsigned short* Cb = (unsigned short*)Cp;
    #pragma unroll
    for (int mt = 0; mt < 2; ++mt)
        #pragma unroll
        for (int nt = 0; nt < 4; ++nt) {
            const int row0 = rowBase + wm + mt * 16 + quad * 4;
            const int col  = colBase + wn + nt * 16 + lr;
            const float b = BIAS ? bias[col] : 0.f;
            #pragma unroll
            for (int r = 0; r < 4; ++r) {
                const int row = row0 + r;
                float v = acc[mt][nt][r] + b;
                if (RES)     v += resid[(long)row * ldc + col];
                if (OUT_F32) Cf[(long)row * ldc + col] = v;
                else         Cb[(long)row * ldc + col] = f2bf(v);
            }
        }
}

// Fused attention, 8-WAVE blocks: 64 Q-rows x 256 V-cols, 512 blocks (2 cs x 32
// qt x 8 z), 2 blocks/CU = 16 waves/CU (same occupancy as r6's 4x4-wave).
// Waves 0-3 ("S-waves"): per-wave S+exp profile IDENTICAL to the proven r2/r4
// kernel (16 rows x 64 keys each — latency hiding intact; r3 lesson respected).
// Waves 4-7 ("stage-waves"): K-tile staging + barrier wait (slack absorbs their
// V-load latency). ALL 8 waves run PV on their own 32-col slice, sharing P via
// the existing sP buffer. Net chip-wide: S-MFMA, exp/cvt, sP-write conflicts,
// and K L2 traffic all HALVED; PV unchanged.
__global__ __launch_bounds__(512, 4)
void flash_attn(const unsigned short* __restrict__ QK,  // [8*2048][128] (Q|K)
                const unsigned short* __restrict__ VT,  // [8][512][2048]
                unsigned short* __restrict__ O)         // [8*2048][512]
{
    __shared__ __align__(16) unsigned short sK[2][64 * 64];   // 2 x 8 KB
    __shared__ __align__(16) unsigned short sP[2][64 * 72];   // 2 x 9 KB
    __shared__ float sL[64];

    const int bid = blockIdx.x;
    const int z  = bid & 7;          // batch -> XCD (round-robin dispatch)
    const int rr = bid >> 3;
    const int cs = rr & 1;           // 256-col split
    const int qt = rr >> 1;          // Q tile (64 rows), 32 tiles

    const int t = threadIdx.x, wave = t >> 6, lane = t & 63;
    const int lr = lane & 15, quad = lane >> 4;
    const int sw = wave & 3;         // role index within the 4-wave group
    const bool isS = wave < 4;       // wave-uniform

    const long qrow0 = (long)z * 2048 + qt * 64;
    // Q A-frags: S-waves only (rows sw*16 + lr)
    bf16x8 qa0, qa1;
    if (isS) {
        const unsigned short* qp = QK + (qrow0 + sw * 16 + lr) * 128 + quad * 8;
        qa0 = *(const bf16x8*)(qp);
        qa1 = *(const bf16x8*)(qp + 32);
    }

    // K rows at QK[z*2048+key][64..127]: 256 B row stride
    const char* Kb = (const char*)(QK + (long)z * 2048 * 128 + 64);
    const unsigned short* Vb = VT + (long)z * 512 * 2048
                                  + ((long)cs * 256 + wave * 32) * 2048;

    // staging (stage-waves): wave sw stages keys sw*16..+15; PRE-SWIZZLED source
    const long stg_go = (long)(sw * 16 + (lane >> 3)) * 256
                      + (((lane & 7) ^ (lane >> 3)) << 4);
    const int swq = (lr & 7) << 4;   // read-side XOR, (key&7)==(lr&7)

    f32x4 acc[4][2];   // [mt][nt]: rows mt*16+quad*4+r, cols cs*256+wave*32+nt*16+lr
    #pragma unroll
    for (int mt = 0; mt < 4; ++mt)
        #pragma unroll
        for (int nt = 0; nt < 2; ++nt) acc[mt][nt] = (f32x4){0.f, 0.f, 0.f, 0.f};
    float lsum[4] = {0.f, 0.f, 0.f, 0.f};

    if (!isS) {   // prologue: stage-waves stage K tile 0 into sK[0]
        const char* gk = Kb + stg_go;
        char* lk = (char*)sK[0] + sw * 2048;
        gld_lds16(gk, lk);
        gld_lds16(gk + 2048, lk + 1024);
    }
    __syncthreads();

    int cur = 0;
    for (int kt = 0; kt < 32; ++kt) {
        const int key0 = kt * 64;

        // prefetch V frags for THIS tile (S-waves: hides under S+exp; stage-waves:
        // latency absorbed by their barrier wait)
        bf16x8 vv[2][2];
        #pragma unroll
        for (int nt = 0; nt < 2; ++nt) {
            const unsigned short* vp = Vb + (long)(nt * 16 + lr) * 2048 + key0 + quad * 8;
            vv[nt][0] = *(const bf16x8*)(vp);
            vv[nt][1] = *(const bf16x8*)(vp + 32);
        }

        if (!isS) {
            // stage-waves: async-stage NEXT K tile
            if (kt < 31) {
                const char* gk = Kb + (long)(kt + 1) * 16384 + stg_go;
                char* lk = (char*)sK[cur ^ 1] + sw * 2048;
                gld_lds16(gk, lk);
                gld_lds16(gk + 2048, lk + 1024);
            }
        } else {
            // S-waves: S = Q K^T for rows sw*16..+15 x all 64 keys
            const char* sKc = (const char*)sK[cur];
            __bf16* sPb = (__bf16*)sP[cur];
            #pragma unroll
            for (int nt = 0; nt < 4; ++nt) {
                const int kb = (nt * 16 + lr) * 128;
                bf16x8 k0 = *(const bf16x8*)(sKc + kb + ((quad * 16) ^ swq));
                bf16x8 k1 = *(const bf16x8*)(sKc + kb + ((quad * 16 + 64) ^ swq));
                f32x4 sv = (f32x4){0.f, 0.f, 0.f, 0.f};
                sv = __builtin_amdgcn_mfma_f32_16x16x32_bf16(qa0, k0, sv, 0, 0, 0);
                sv = __builtin_amdgcn_mfma_f32_16x16x32_bf16(qa1, k1, sv, 0, 0, 0);
                #pragma unroll
                for (int r = 0; r < 4; ++r) {
                    const float e = __expf(sv[r]);
                    const __bf16 pb = (__bf16)e;       // v_cvt RNE
                    lsum[r] += (float)pb;
                    sPb[(sw * 16 + quad * 4 + r) * 72 + nt * 16 + lr] = pb;
                }
            }
        }

        __syncthreads();   // publishes sP[cur], drains async sK[cur^1] stages

        // O += P V  (all 8 waves; A-frags of P from LDS, B-frags prefetched)
        const unsigned short* sPc = sP[cur];
        __builtin_amdgcn_s_setprio(1);
        #pragma unroll
        for (int mt = 0; mt < 4; ++mt) {
            const unsigned short* pp = &sPc[(mt * 16 + lr) * 72 + quad * 8];
            bf16x8 p0 = *(const bf16x8*)(pp);
            bf16x8 p1 = *(const bf16x8*)(pp + 32);
            acc[mt][0] = __builtin_amdgcn_mfma_f32_16x16x32_bf16(p0, vv[0][0], acc[mt][0], 0, 0, 0);
            acc[mt][0] = __builtin_amdgcn_mfma_f32_16x16x32_bf16(p1, vv[0][1], acc[mt][0], 0, 0, 0);
            acc[mt][1] = __builtin_amdgcn_mfma_f32_16x16x32_bf16(p0, vv[1][0], acc[mt][1], 0, 0, 0);
            acc[mt][1] = __builtin_amdgcn_mfma_f32_16x16x32_bf16(p1, vv[1][1], acc[mt][1], 0, 0, 0);
        }
        __builtin_amdgcn_s_setprio(0);
        cur ^= 1;
    }

    // row sums (S-waves) -> sL -> all waves, then O = acc / l
    if (isS) {
        #pragma unroll
        for (int r = 0; r < 4; ++r) {
            float v = lsum[r];
            v += __shfl_xor(v, 1); v += __shfl_xor(v, 2);
            v += __shfl_xor(v, 4); v += __shfl_xor(v, 8);
            lsum[r] = v;
        }
        if (lr == 0) {
            #pragma unroll
            for (int r = 0; r < 4; ++r) sL[sw * 16 + quad * 4 + r] = lsum[r];
        }
    }
    __syncthreads();

    #pragma unroll
    for (int mt = 0; mt < 4; ++mt) {
        float inv[4];
        #pragma unroll
        for (int r = 0; r < 4; ++r) inv[r] = 1.0f / sL[mt * 16 + quad * 4 + r];
        #pragma unroll
        for (int nt = 0; nt < 2; ++nt) {
            const int col = cs * 256 + wave * 32 + nt * 16 + lr;
            #pragma unroll
            for (int r = 0; r < 4; ++r) {
                const long row = qrow0 + mt * 16 + quad * 4 + r;
                O[row * 512 + col] = f2bf(acc[mt][nt][r] * inv[r]);
            }
        }
    }
}

extern "C" void kernel_launch(void* const* d_in, const int* in_sizes, int n_in,
                              void* d_out, int out_size, void* d_ws, size_t ws_size,
                              hipStream_t stream)
{
    const float* x  = (const float*)d_in[0];
    const float* wq = (const float*)d_in[1];
    const float* bq = (const float*)d_in[2];
    const float* wk = (const float*)d_in[3];
    const float* bk = (const float*)d_in[4];
    const float* wv = (const float*)d_in[5];
    const float* bv = (const float*)d_in[6];
    const float* wo = (const float*)d_in[7];
    const float* bo = (const float*)d_in[8];

    const int W = 512;
    float* out = (float*)d_out;
    dim3 blk(256);
    char* ws = (char*)d_ws;

    const size_t NEED = 56ull << 20;
    if (ws_size < NEED) return;  // zero-output signature

    unsigned short* QK    = (unsigned short*)(ws);                  //  4 MB [16384 x 128] (Q|K)
    unsigned short* VT    = (unsigned short*)(ws + ( 4ull << 20));  // 16 MB [8][512][2048]
    unsigned short* O     = (unsigned short*)(ws + (20ull << 20));  // 16 MB [16384 x 512]
    unsigned short* xb    = (unsigned short*)(ws + (36ull << 20));  // 16 MB [16384 x 512]
    unsigned short* wAllT = (unsigned short*)(ws + (52ull << 20));  // 640 KB [640][512]
    unsigned short* woT   = (unsigned short*)(ws + (53ull << 20));  // 512 KB [512][512]
    float*          ball  = (float*)         (ws + (53ull << 20) + (512ull << 10)); // 2.5 KB

    // pack: x->bf16, bias concat, weights -> bf16 B^T layouts (merged launch)
    pack<<<dim3(2048 + 256), blk, 0, stream>>>(x, xb, bq, bk, bv, ball,
                                               wv, wo, wq, wk, wAllT, woT);

    // Fused QKV projection: [QK | V] = xb @ [wq|wk|wv] + [bq|bk|bv]
    gemm64<true, false, false, true, 5><<<dim3(1280), blk, 0, stream>>>(
        xb, W, wAllT, W, QK, 128, VT, ball, nullptr, W);

    // Fused attention (no S): O = softmax(Q K^T) V — 8-wave blocks, 512 blocks
    flash_attn<<<dim3(512), dim3(512), 0, stream>>>(QK, VT, O);

    // out = O @ wo + bo + x  (fp32)
    gemm64<true, true, true, false, 4><<<dim3(1024), blk, 0, stream>>>(
        O, W, woT, W, out, W, nullptr, bo, x, W);
}